// Round 1
// 299.273 us; speedup vs baseline: 1.1224x; 1.1224x over previous
//
#include <hip/hip_runtime.h>
#include <stdint.h>

// Problem dims (fixed by the reference)
constexpr int B_ = 2, S_ = 2048, E_ = 1024, H_ = 16, D_ = 64;
constexpr int M_ = B_ * S_;              // 4096 rows
constexpr size_t ME_ = (size_t)M_ * E_;  // 4,194,304

typedef unsigned short u16;
typedef __attribute__((ext_vector_type(8))) short short8;
typedef __attribute__((ext_vector_type(4))) float f32x4;

__device__ __forceinline__ float bf2f(u16 u) {
  union { uint32_t i; float f; } v; v.i = ((uint32_t)u) << 16; return v.f;
}
__device__ __forceinline__ u16 f2bf(float f) {
  uint32_t u = __float_as_uint(f);
  return (u16)((u + 0x7FFFu + ((u >> 16) & 1u)) >> 16);  // RNE
}
// truncation split: hi = trunc16(x), lo = trunc16(x - hi). hi+lo ~ x to 2^-17.
__device__ __forceinline__ void tsplit(float x, u16& hi, u16& lo) {
  const uint32_t u = __float_as_uint(x);
  hi = (u16)(u >> 16);
  const float hif = __uint_as_float(u & 0xFFFF0000u);
  lo = (u16)(__float_as_uint(x - hif) >> 16);
}

// ---------------------------------------------------------------------------
// Kernel 0: split fp32 -> (hi, lo) bf16 pair, elementwise (weights).
// ---------------------------------------------------------------------------
__global__ __launch_bounds__(256) void split_f32_kernel(
    const float* __restrict__ src, u16* __restrict__ hi, u16* __restrict__ lo, int n4)
{
  const int i = blockIdx.x * 256 + threadIdx.x;
  if (i >= n4) return;
  const float4 x = ((const float4*)src)[i];
  ushort4 h, l;
  tsplit(x.x, h.x, l.x); tsplit(x.y, h.y, l.y);
  tsplit(x.z, h.z, l.z); tsplit(x.w, h.w, l.w);
  ((ushort4*)hi)[i] = h;
  ((ushort4*)lo)[i] = l;
}

// ---------------------------------------------------------------------------
// Kernel 0b: per-batch exclusive prefix scan of the key mask.
// cpos[b][s] = # unmasked keys before s; nk[b] = total unmasked keys.
// ---------------------------------------------------------------------------
__global__ __launch_bounds__(256) void mask_scan_kernel(
    const int* __restrict__ mask, int* __restrict__ cpos, int* __restrict__ nk)
{
  __shared__ int tmp[256];
  __shared__ int coff;
  const int b = blockIdx.x, t = threadIdx.x;
  if (t == 0) coff = 0;
  __syncthreads();
  for (int c = 0; c < S_; c += 256) {
    const int m = (mask[b * S_ + c + t] != 0) ? 1 : 0;
    int x = m;
    tmp[t] = x;
    __syncthreads();
#pragma unroll
    for (int off = 1; off < 256; off <<= 1) {
      const int v = (t >= off) ? tmp[t - off] : 0;
      __syncthreads();
      x += v;
      tmp[t] = x;
      __syncthreads();
    }
    const int base = coff;
    cpos[b * S_ + c + t] = base + x - m;   // exclusive scan
    __syncthreads();
    if (t == 255) coff = base + x;         // x at t=255 = chunk total
    __syncthreads();
  }
  if (t == 0) nk[b] = coff;
}

// ---------------------------------------------------------------------------
// Kernel 1: QKV projection, split-bf16 MFMA, register-prefetch pipeline.
// 128x128 tile / block, 4 waves (2x2), each wave 64x64 = 4x4 mfma 16x16x32.
// Epilogue: Q via LDS transpose -> b128 row stores (hi & lo passes);
//           K same but rows COMPACTED to unmasked key positions;
//           V -> bf16 [B,H,D,S] with columns compacted (predicated stores).
// ---------------------------------------------------------------------------
__global__ __launch_bounds__(256) void gemm_qkv_kernel(
    const float* __restrict__ q, const float* __restrict__ k, const float* __restrict__ v,
    const u16* __restrict__ WHi, const u16* __restrict__ WLo,
    const float* __restrict__ bias,
    const int* __restrict__ Msk, const int* __restrict__ Cpos,
    u16* __restrict__ QpHi, u16* __restrict__ QpLo,
    u16* __restrict__ KpHi, u16* __restrict__ KpLo,
    u16* __restrict__ Vp)
{
  __shared__ __align__(16) short smem[20480];  // 40,960 B
  short* Ah = smem;            // 128*40
  short* Al = smem + 5120;
  short* Bh = smem + 10240;
  short* Bl = smem + 15360;

  const int t = threadIdx.x;
  const int m0 = blockIdx.x * 128;
  const int n0g = blockIdx.y * 128;          // global col in [0, 3072)
  const int proj = n0g >> 10;
  const int nloc = n0g & (E_ - 1);
  const float* A = (proj == 0) ? q : (proj == 1) ? k : v;
  const bool split = (proj < 2);

  const int w = t >> 6, lane = t & 63;
  const int g = lane >> 4, lc = lane & 15;
  const int wm = w & 1, wn = w >> 1;
  const int srow = t >> 1, sh = (t & 1) * 16; // staging: 2 threads/row, 16 elems

  const float* Ab = A + (size_t)(m0 + srow) * E_ + sh;
  const u16* Bhb = WHi + (size_t)(n0g + srow) * E_ + sh;
  const u16* Blb = WLo + (size_t)(n0g + srow) * E_ + sh;

  f32x4 acc[4][4];
#pragma unroll
  for (int i = 0; i < 4; ++i)
#pragma unroll
    for (int j = 0; j < 4; ++j) acc[i][j] = (f32x4){0.f, 0.f, 0.f, 0.f};

  // prefetch registers
  float4 ar[4]; short8 br[2], cr[2];
#pragma unroll
  for (int i = 0; i < 4; ++i) ar[i] = *(const float4*)(Ab + 4 * i);
  br[0] = *(const short8*)(Bhb);     br[1] = *(const short8*)(Bhb + 8);
  if (split) { cr[0] = *(const short8*)(Blb); cr[1] = *(const short8*)(Blb + 8); }

  for (int k0 = 0; k0 < E_; k0 += 32) {
    __syncthreads();                 // previous iteration's frag reads done
    // store staged regs -> LDS (A converted hi/lo by truncation split)
#pragma unroll
    for (int i = 0; i < 4; ++i) {
      ushort4 h, l;
      tsplit(ar[i].x, h.x, l.x); tsplit(ar[i].y, h.y, l.y);
      tsplit(ar[i].z, h.z, l.z); tsplit(ar[i].w, h.w, l.w);
      *(ushort4*)&Ah[srow * 40 + sh + 4 * i] = h;
      if (split) *(ushort4*)&Al[srow * 40 + sh + 4 * i] = l;
    }
    *(short8*)&Bh[srow * 40 + sh]     = br[0];
    *(short8*)&Bh[srow * 40 + sh + 8] = br[1];
    if (split) {
      *(short8*)&Bl[srow * 40 + sh]     = cr[0];
      *(short8*)&Bl[srow * 40 + sh + 8] = cr[1];
    }
    __syncthreads();
    // prefetch next K-step (latency hidden behind frag reads + MFMA)
    if (k0 + 32 < E_) {
#pragma unroll
      for (int i = 0; i < 4; ++i) ar[i] = *(const float4*)(Ab + k0 + 32 + 4 * i);
      br[0] = *(const short8*)(Bhb + k0 + 32); br[1] = *(const short8*)(Bhb + k0 + 40);
      if (split) {
        cr[0] = *(const short8*)(Blb + k0 + 32); cr[1] = *(const short8*)(Blb + k0 + 40);
      }
    }

    short8 ah[4], al[4], bh[4], bl[4];
#pragma unroll
    for (int mt = 0; mt < 4; ++mt) {
      const int ro = (wm * 64 + mt * 16 + lc) * 40 + g * 8;
      ah[mt] = *(const short8*)&Ah[ro];
      if (split) al[mt] = *(const short8*)&Al[ro];
    }
#pragma unroll
    for (int nt = 0; nt < 4; ++nt) {
      const int ro = (wn * 64 + nt * 16 + lc) * 40 + g * 8;
      bh[nt] = *(const short8*)&Bh[ro];
      if (split) bl[nt] = *(const short8*)&Bl[ro];
    }
#pragma unroll
    for (int mt = 0; mt < 4; ++mt)
#pragma unroll
      for (int nt = 0; nt < 4; ++nt) {
        f32x4 a = acc[mt][nt];
        a = __builtin_amdgcn_mfma_f32_16x16x32_bf16(ah[mt], bh[nt], a, 0, 0, 0);
        if (split) {
          a = __builtin_amdgcn_mfma_f32_16x16x32_bf16(ah[mt], bl[nt], a, 0, 0, 0);
          a = __builtin_amdgcn_mfma_f32_16x16x32_bf16(al[mt], bh[nt], a, 0, 0, 0);
        }
        acc[mt][nt] = a;
      }
  }

  // epilogue
  float bs[4];
#pragma unroll
  for (int nt = 0; nt < 4; ++nt) bs[nt] = bias[n0g + wn * 64 + nt * 16 + lc];

  if (proj < 2) {
    // each wave's 64 n-cols = exactly one head
    u16* Hi = (proj == 0) ? QpHi : KpHi;
    u16* Lo = (proj == 0) ? QpLo : KpLo;
    const int hwave = (nloc + wn * 64) >> 6;
    short* T = smem + w * 4608;               // per-wave [64][72] u16
    const int mrow = m0 + wm * 64 + lane;
    const int bb = mrow >> 11, s = mrow & (S_ - 1);
    bool ok = true;
    int srow_out = s;
    if (proj == 1) {                          // K: compact rows
      ok = (Msk[bb * S_ + s] != 0);
      srow_out = Cpos[bb * S_ + s];
    }
    const size_t rowb = (((size_t)(bb * H_ + hwave)) * S_ + srow_out) * D_;
#pragma unroll
    for (int pass = 0; pass < 2; ++pass) {
      __syncthreads();                        // LDS free / prev pass reads done
#pragma unroll
      for (int nt = 0; nt < 4; ++nt)
#pragma unroll
        for (int mt = 0; mt < 4; ++mt)
#pragma unroll
          for (int r = 0; r < 4; ++r) {
            const float val = acc[mt][nt][r] + bs[nt];
            const uint32_t u = __float_as_uint(val);
            u16 x;
            if (pass == 0) x = (u16)(u >> 16);
            else {
              const float hif = __uint_as_float(u & 0xFFFF0000u);
              x = (u16)(__float_as_uint(val - hif) >> 16);
            }
            T[(mt * 16 + g * 4 + r) * 72 + nt * 16 + lc] = (short)x;
          }
      __syncthreads();
      u16* dst = (pass == 0) ? Hi : Lo;
      if (ok) {
#pragma unroll
        for (int j = 0; j < 8; ++j)
          *(short8*)&dst[rowb + 8 * j] = *(const short8*)&T[lane * 72 + 8 * j];
      }
    }
  } else {
    // V: [B,H,D,S] layout with key columns compacted (predicated scalar stores)
#pragma unroll
    for (int mt = 0; mt < 4; ++mt) {
      const int mrow = m0 + wm * 64 + mt * 16 + g * 4;
      const int bb = mrow >> 11, sbase = mrow & (S_ - 1);
      const int4 mk = *(const int4*)&Msk[bb * S_ + sbase];
      const int4 cp = *(const int4*)&Cpos[bb * S_ + sbase];
      const int mkA[4] = {mk.x, mk.y, mk.z, mk.w};
      const int cpA[4] = {cp.x, cp.y, cp.z, cp.w};
#pragma unroll
      for (int nt = 0; nt < 4; ++nt) {
        const int nE = nloc + wn * 64 + nt * 16 + lc;
        const int h = nE >> 6, d = nE & 63;
        const size_t rb = (((size_t)(bb * H_ + h)) * D_ + d) * S_;
#pragma unroll
        for (int r = 0; r < 4; ++r) {
          if (mkA[r]) Vp[rb + cpA[r]] = f2bf(acc[mt][nt][r] + bs[nt]);
        }
      }
    }
  }
}

// ---------------------------------------------------------------------------
// Kernel 2: MFMA flash attention v5.
// v4 + key compaction (loop over ceil(nk/64) tiles, no mask loads) +
// 64 q-rows/block (1 q-set per wave) for 4 blocks/CU occupancy.
// ---------------------------------------------------------------------------
__global__ __launch_bounds__(256, 4) void attn_mfma_kernel(
    const u16* __restrict__ QpHi, const u16* __restrict__ QpLo,
    const u16* __restrict__ KpHi, const u16* __restrict__ KpLo,
    const u16* __restrict__ Vp,
    const int* __restrict__ nkArr,
    u16* __restrict__ AOHi)
{
  __shared__ __align__(16) short sm[18432];  // 36,864 B
  short* Khi = sm;                           // [64][72]
  short* Klo = sm + 4608;                    // [64][72]
  short* Vt  = sm + 9216;                    // [64][72] (d-major)
  short* Pb  = sm + 13824;                   // 4 waves x [16][72]

  const int t = threadIdx.x;
  const int w = t >> 6, lane = t & 63;
  const int g = lane >> 4, lc = lane & 15;
  const int bh = blockIdx.y;
  const int b = bh >> 4, hh = bh & 15;
  const int q0 = blockIdx.x * 64;
  const size_t hb = (size_t)bh * S_ * D_;
  const u16* QgH = QpHi + hb;
  const u16* QgL = QpLo + hb;
  const u16* KgH = KpHi + hb;
  const u16* KgL = KpLo + hb;
  const u16* Vg  = Vp + hb;
  short* Pw = Pb + w * 1152;

  const int nk = nkArr[b];
  const int kend = ((nk + 63) >> 6) << 6;    // tiles of 64 compacted keys

  // ---- Q A-frags direct from global (lane lc = q-row, k = 8g..8g+7) ----
  short8 qh[2], ql[2];
  {
    const size_t base = (size_t)(q0 + 16 * w + lc) * D_ + 8 * g;
    qh[0] = *(const short8*)&QgH[base];
    qh[1] = *(const short8*)&QgH[base + 32];
    ql[0] = *(const short8*)&QgL[base];
    ql[1] = *(const short8*)&QgL[base + 32];
  }

  // ones column in B (n=0): lanes with lc==0 hold bf16(1.0) for all k
  short8 ones8 = {0, 0, 0, 0, 0, 0, 0, 0};
  if (lc == 0) {
    const short o = (short)0x3F80;
    ones8 = (short8){o, o, o, o, o, o, o, o};
  }

  f32x4 O[4];
  f32x4 Ol = (f32x4){0.f, 0.f, 0.f, 0.f};
#pragma unroll
  for (int dt = 0; dt < 4; ++dt) O[dt] = (f32x4){0.f, 0.f, 0.f, 0.f};
  float mst[4] = {-INFINITY, -INFINITY, -INFINITY, -INFINITY};

  const int srow = t >> 2, sc16 = (t & 3) * 16;   // staging: 4 threads/row

  // staging prefetch registers (K hi/lo, V)
  short8 kr[2], lr[2], vr[2];
  kr[0] = *(const short8*)&KgH[srow * D_ + sc16];
  kr[1] = *(const short8*)&KgH[srow * D_ + sc16 + 8];
  lr[0] = *(const short8*)&KgL[srow * D_ + sc16];
  lr[1] = *(const short8*)&KgL[srow * D_ + sc16 + 8];
  vr[0] = *(const short8*)&Vg[srow * S_ + sc16];
  vr[1] = *(const short8*)&Vg[srow * S_ + sc16 + 8];

  for (int kt = 0; kt < kend; kt += 64) {
    __syncthreads();                         // previous tile fully consumed
    *(short8*)&Khi[srow * 72 + sc16]     = kr[0];
    *(short8*)&Khi[srow * 72 + sc16 + 8] = kr[1];
    *(short8*)&Klo[srow * 72 + sc16]     = lr[0];
    *(short8*)&Klo[srow * 72 + sc16 + 8] = lr[1];
    *(short8*)&Vt[srow * 72 + sc16]      = vr[0];
    *(short8*)&Vt[srow * 72 + sc16 + 8]  = vr[1];
    __syncthreads();
    if (kt + 64 < kend) {                    // prefetch next tile
      const int kn = kt + 64;
      kr[0] = *(const short8*)&KgH[(kn + srow) * D_ + sc16];
      kr[1] = *(const short8*)&KgH[(kn + srow) * D_ + sc16 + 8];
      lr[0] = *(const short8*)&KgL[(kn + srow) * D_ + sc16];
      lr[1] = *(const short8*)&KgL[(kn + srow) * D_ + sc16 + 8];
      vr[0] = *(const short8*)&Vg[srow * S_ + kn + sc16];
      vr[1] = *(const short8*)&Vg[srow * S_ + kn + sc16 + 8];
    }

    // ---- scores: S[16q x 64k] ----
    f32x4 sc[4];
#pragma unroll
    for (int kt16 = 0; kt16 < 4; ++kt16) {
      const int ko = (16 * kt16 + lc) * 72 + 8 * g;
      const short8 kh0 = *(const short8*)&Khi[ko];
      const short8 kh1 = *(const short8*)&Khi[ko + 32];
      const short8 kl0 = *(const short8*)&Klo[ko];
      const short8 kl1 = *(const short8*)&Klo[ko + 32];
      f32x4 a = {0.f, 0.f, 0.f, 0.f};
      a = __builtin_amdgcn_mfma_f32_16x16x32_bf16(qh[0], kh0, a, 0, 0, 0);
      a = __builtin_amdgcn_mfma_f32_16x16x32_bf16(qh[1], kh1, a, 0, 0, 0);
      a = __builtin_amdgcn_mfma_f32_16x16x32_bf16(qh[0], kl0, a, 0, 0, 0);
      a = __builtin_amdgcn_mfma_f32_16x16x32_bf16(qh[1], kl1, a, 0, 0, 0);
      a = __builtin_amdgcn_mfma_f32_16x16x32_bf16(ql[0], kh0, a, 0, 0, 0);
      a = __builtin_amdgcn_mfma_f32_16x16x32_bf16(ql[1], kh1, a, 0, 0, 0);
      sc[kt16] = a;
    }

    // ---- tail masking: compacted cols >= nk are padding (garbage K) ----
    if (kt + 64 > nk) {
#pragma unroll
      for (int kt16 = 0; kt16 < 4; ++kt16) {
        if (kt + 16 * kt16 + lc >= nk) {
          sc[kt16][0] = -1e20f; sc[kt16][1] = -1e20f;
          sc[kt16][2] = -1e20f; sc[kt16][3] = -1e20f;
        }
      }
    }

    // ---- online max + exp (max butterfly only; sum comes from MFMA) ----
    float al[4];
#pragma unroll
    for (int r = 0; r < 4; ++r) {
      float vv = fmaxf(fmaxf(sc[0][r], sc[1][r]), fmaxf(sc[2][r], sc[3][r]));
      vv = fmaxf(vv, __shfl_xor(vv, 1));
      vv = fmaxf(vv, __shfl_xor(vv, 2));
      vv = fmaxf(vv, __shfl_xor(vv, 4));
      vv = fmaxf(vv, __shfl_xor(vv, 8));
      const float mn = fmaxf(mst[r], vv);
      al[r] = __expf(mst[r] - mn);           // first tile: exp(-inf)=0
      mst[r] = mn;
    }
#pragma unroll
    for (int kt16 = 0; kt16 < 4; ++kt16) {
#pragma unroll
      for (int r = 0; r < 4; ++r)
        sc[kt16][r] = __expf(sc[kt16][r] - mst[r]);
    }
    const f32x4 alv = {al[0], al[1], al[2], al[3]};
    O[0] *= alv; O[1] *= alv; O[2] *= alv; O[3] *= alv;
    Ol *= alv;
    // P: C-layout regs -> bf16 LDS (A-layout source for PV)
#pragma unroll
    for (int kt16 = 0; kt16 < 4; ++kt16) {
#pragma unroll
      for (int r = 0; r < 4; ++r)
        Pw[(4 * g + r) * 72 + 16 * kt16 + lc] = (short)f2bf(sc[kt16][r]);
    }

    // ---- PV + denominator via ones ----
    short8 pa[2];
    pa[0] = *(const short8*)&Pw[lc * 72 + 8 * g];
    pa[1] = *(const short8*)&Pw[lc * 72 + 32 + 8 * g];
    Ol = __builtin_amdgcn_mfma_f32_16x16x32_bf16(pa[0], ones8, Ol, 0, 0, 0);
    Ol = __builtin_amdgcn_mfma_f32_16x16x32_bf16(pa[1], ones8, Ol, 0, 0, 0);
#pragma unroll
    for (int dt = 0; dt < 4; ++dt) {
      const int vo = (16 * dt + lc) * 72 + 8 * g;
      const short8 vb0 = *(const short8*)&Vt[vo];
      const short8 vb1 = *(const short8*)&Vt[vo + 32];
      O[dt] = __builtin_amdgcn_mfma_f32_16x16x32_bf16(pa[0], vb0, O[dt], 0, 0, 0);
      O[dt] = __builtin_amdgcn_mfma_f32_16x16x32_bf16(pa[1], vb1, O[dt], 0, 0, 0);
    }
  }

  // ---- epilogue: broadcast denominator (col 0 on lanes lc==0), normalize ----
#pragma unroll
  for (int r = 0; r < 4; ++r) {
    const float lv = __shfl(Ol[r], lane & 48);
    const float lir = 1.0f / lv;
    const int qrow = q0 + 16 * w + 4 * g + r;
    const size_t rowb = (size_t)(b * S_ + qrow) * E_ + hh * 64;
#pragma unroll
    for (int dt = 0; dt < 4; ++dt)
      AOHi[rowb + dt * 16 + lc] = f2bf(O[dt][r] * lir);
  }
}

// ---------------------------------------------------------------------------
// Kernel 3: output projection, single-bf16 MFMA, register prefetch.
// ---------------------------------------------------------------------------
__global__ __launch_bounds__(256) void gemm_out_kernel(
    const u16* __restrict__ AHi,
    const u16* __restrict__ WHi,
    const float* __restrict__ bias, float* __restrict__ out)
{
  __shared__ __align__(16) short Ah[128 * 40];
  __shared__ __align__(16) short Bh[128 * 40];

  const int t = threadIdx.x;
  const int m0 = blockIdx.x * 128;
  const int n0 = blockIdx.y * 128;
  const int w = t >> 6, lane = t & 63;
  const int g = lane >> 4, lc = lane & 15;
  const int wm = w & 1, wn = w >> 1;
  const int srow = t >> 1, sh = (t & 1) * 16;

  const u16* Ahb = AHi + (size_t)(m0 + srow) * E_ + sh;
  const u16* Bhb = WHi + (size_t)(n0 + srow) * E_ + sh;

  f32x4 acc[4][4];
#pragma unroll
  for (int i = 0; i < 4; ++i)
#pragma unroll
    for (int j = 0; j < 4; ++j) acc[i][j] = (f32x4){0.f, 0.f, 0.f, 0.f};

  short8 arr[2], brr[2];
  arr[0] = *(const short8*)(Ahb); arr[1] = *(const short8*)(Ahb + 8);
  brr[0] = *(const short8*)(Bhb); brr[1] = *(const short8*)(Bhb + 8);

  for (int k0 = 0; k0 < E_; k0 += 32) {
    __syncthreads();
    *(short8*)&Ah[srow * 40 + sh]     = arr[0];
    *(short8*)&Ah[srow * 40 + sh + 8] = arr[1];
    *(short8*)&Bh[srow * 40 + sh]     = brr[0];
    *(short8*)&Bh[srow * 40 + sh + 8] = brr[1];
    __syncthreads();
    if (k0 + 32 < E_) {
      arr[0] = *(const short8*)(Ahb + k0 + 32); arr[1] = *(const short8*)(Ahb + k0 + 40);
      brr[0] = *(const short8*)(Bhb + k0 + 32); brr[1] = *(const short8*)(Bhb + k0 + 40);
    }

    short8 ah[4], bh[4];
#pragma unroll
    for (int mt = 0; mt < 4; ++mt)
      ah[mt] = *(const short8*)&Ah[(wm * 64 + mt * 16 + lc) * 40 + g * 8];
#pragma unroll
    for (int nt = 0; nt < 4; ++nt)
      bh[nt] = *(const short8*)&Bh[(wn * 64 + nt * 16 + lc) * 40 + g * 8];
#pragma unroll
    for (int mt = 0; mt < 4; ++mt)
#pragma unroll
      for (int nt = 0; nt < 4; ++nt)
        acc[mt][nt] = __builtin_amdgcn_mfma_f32_16x16x32_bf16(ah[mt], bh[nt], acc[mt][nt], 0, 0, 0);
  }

  float bs[4];
#pragma unroll
  for (int nt = 0; nt < 4; ++nt) bs[nt] = bias[n0 + wn * 64 + nt * 16 + lc];
#pragma unroll
  for (int nt = 0; nt < 4; ++nt) {
    const int nc = n0 + wn * 64 + nt * 16 + lc;
#pragma unroll
    for (int mt = 0; mt < 4; ++mt) {
#pragma unroll
      for (int r = 0; r < 4; ++r) {
        const int mrow = m0 + wm * 64 + mt * 16 + g * 4 + r;
        out[(size_t)mrow * E_ + nc] = acc[mt][nt][r] + bs[nt];
      }
    }
  }
}

// ---------------------------------------------------------------------------
extern "C" void kernel_launch(void* const* d_in, const int* in_sizes, int n_in,
                              void* d_out, int out_size, void* d_ws, size_t ws_size,
                              hipStream_t stream) {
  const float* q    = (const float*)d_in[0];
  const float* k    = (const float*)d_in[1];
  const float* v    = (const float*)d_in[2];
  const int*   mask = (const int*)d_in[3];
  const float* Wqkv = (const float*)d_in[4];
  const float* bqkv = (const float*)d_in[5];
  const float* Wout = (const float*)d_in[6];
  const float* bout = (const float*)d_in[7];
  float* out = (float*)d_out;

  // Workspace layout (64 MB).
  char* wsb = (char*)d_ws;
  u16* WqkvHi = (u16*)(wsb + 0);          //  6 MB
  u16* WqkvLo = (u16*)(wsb + 6291456);    //  6 MB
  u16* WoutHi = (u16*)(wsb + 12582912);   //  2 MB
  // WoutLo region (2 MB at 14680064) is scratch: split writes it, then the
  // scan kernel reuses the space for cpos/nk (stream-ordered, safe).
  int* Cpos   = (int*)(wsb + 14680064);   // 16 KB (B*S ints)
  int* Nk     = (int*)(wsb + 14680064 + 16384);  // 8 B
  u16* WoutLo = (u16*)(wsb + 14680064);   // (written then overwritten, unused)
  u16* QpHi   = (u16*)(wsb + 16777216);   //  8 MB
  u16* QpLo   = (u16*)(wsb + 25165824);   //  8 MB
  u16* KpHi   = (u16*)(wsb + 33554432);   //  8 MB
  u16* KpLo   = (u16*)(wsb + 41943040);   //  8 MB
  u16* Vp     = (u16*)(wsb + 50331648);   //  8 MB
  u16* AOHi   = (u16*)(wsb + 58720256);   //  8 MB

  hipLaunchKernelGGL(split_f32_kernel, dim3(3072), dim3(256), 0, stream,
                     Wqkv, WqkvHi, WqkvLo, 786432);
  hipLaunchKernelGGL(split_f32_kernel, dim3(1024), dim3(256), 0, stream,
                     Wout, WoutHi, WoutLo, 262144);
  hipLaunchKernelGGL(mask_scan_kernel, dim3(B_), dim3(256), 0, stream,
                     mask, Cpos, Nk);
  // zero V so padded tail columns (>= nk) contribute exact 0 in PV
  hipMemsetAsync(Vp, 0, 8388608, stream);
  hipLaunchKernelGGL(gemm_qkv_kernel, dim3(M_ / 128, 24), dim3(256), 0, stream,
                     q, k, v, WqkvHi, WqkvLo, bqkv, mask, Cpos,
                     QpHi, QpLo, KpHi, KpLo, Vp);
  hipLaunchKernelGGL(attn_mfma_kernel, dim3(S_ / 64, B_ * H_), dim3(256), 0, stream,
                     QpHi, QpLo, KpHi, KpLo, Vp, Nk, AOHi);
  hipLaunchKernelGGL(gemm_out_kernel, dim3(M_ / 128, E_ / 128), dim3(256), 0, stream,
                     AOHi, WoutHi, bout, out);
}

// Round 2
// 294.429 us; speedup vs baseline: 1.1409x; 1.0165x over previous
//
#include <hip/hip_runtime.h>
#include <stdint.h>

// Problem dims (fixed by the reference)
constexpr int B_ = 2, S_ = 2048, E_ = 1024, H_ = 16, D_ = 64;
constexpr int M_ = B_ * S_;              // 4096 rows
constexpr size_t ME_ = (size_t)M_ * E_;  // 4,194,304

typedef unsigned short u16;
typedef __attribute__((ext_vector_type(8))) short short8;
typedef __attribute__((ext_vector_type(4))) float f32x4;

__device__ __forceinline__ float bf2f(u16 u) {
  union { uint32_t i; float f; } v; v.i = ((uint32_t)u) << 16; return v.f;
}
__device__ __forceinline__ u16 f2bf(float f) {
  uint32_t u = __float_as_uint(f);
  return (u16)((u + 0x7FFFu + ((u >> 16) & 1u)) >> 16);  // RNE
}
// truncation split: hi = trunc16(x), lo = trunc16(x - hi). hi+lo ~ x to 2^-17.
__device__ __forceinline__ void tsplit(float x, u16& hi, u16& lo) {
  const uint32_t u = __float_as_uint(x);
  hi = (u16)(u >> 16);
  const float hif = __uint_as_float(u & 0xFFFF0000u);
  lo = (u16)(__float_as_uint(x - hif) >> 16);
}

// ---------------------------------------------------------------------------
// Kernel 0: split fp32 -> (hi, lo) bf16 pair, elementwise (weights).
// ---------------------------------------------------------------------------
__global__ __launch_bounds__(256) void split_f32_kernel(
    const float* __restrict__ src, u16* __restrict__ hi, u16* __restrict__ lo, int n4)
{
  const int i = blockIdx.x * 256 + threadIdx.x;
  if (i >= n4) return;
  const float4 x = ((const float4*)src)[i];
  ushort4 h, l;
  tsplit(x.x, h.x, l.x); tsplit(x.y, h.y, l.y);
  tsplit(x.z, h.z, l.z); tsplit(x.w, h.w, l.w);
  ((ushort4*)hi)[i] = h;
  ((ushort4*)lo)[i] = l;
}

// ---------------------------------------------------------------------------
// Kernel 0b: per-batch exclusive prefix scan of the key mask.
// ---------------------------------------------------------------------------
__global__ __launch_bounds__(256) void mask_scan_kernel(
    const int* __restrict__ mask, int* __restrict__ cpos, int* __restrict__ nk)
{
  __shared__ int tmp[256];
  __shared__ int coff;
  const int b = blockIdx.x, t = threadIdx.x;
  if (t == 0) coff = 0;
  __syncthreads();
  for (int c = 0; c < S_; c += 256) {
    const int m = (mask[b * S_ + c + t] != 0) ? 1 : 0;
    int x = m;
    tmp[t] = x;
    __syncthreads();
#pragma unroll
    for (int off = 1; off < 256; off <<= 1) {
      const int v = (t >= off) ? tmp[t - off] : 0;
      __syncthreads();
      x += v;
      tmp[t] = x;
      __syncthreads();
    }
    const int base = coff;
    cpos[b * S_ + c + t] = base + x - m;   // exclusive scan
    __syncthreads();
    if (t == 255) coff = base + x;         // x at t=255 = chunk total
    __syncthreads();
  }
  if (t == 0) nk[b] = coff;
}

// ---------------------------------------------------------------------------
// Kernel 1: QKV projection, split-bf16 MFMA, register-prefetch pipeline.
// v2: 128x64 tile / block (grid 32x48 = 1536 blocks -> 6 blocks/CU issued,
// 5 resident by LDS; ~20 waves/CU vs 12 before). 4 waves (2m x 2n), each
// wave 64x32 = 4x2 mfma 16x16x32. LDS 30.7 KB.
// Epilogue: Q via LDS transpose -> row stores (hi & lo passes);
//           K same but rows COMPACTED to unmasked key positions;
//           V -> bf16 [B,H,D,S] with columns compacted (predicated stores).
// ---------------------------------------------------------------------------
__global__ __launch_bounds__(256) void gemm_qkv_kernel(
    const float* __restrict__ q, const float* __restrict__ k, const float* __restrict__ v,
    const u16* __restrict__ WHi, const u16* __restrict__ WLo,
    const float* __restrict__ bias,
    const int* __restrict__ Msk, const int* __restrict__ Cpos,
    u16* __restrict__ QpHi, u16* __restrict__ QpLo,
    u16* __restrict__ KpHi, u16* __restrict__ KpLo,
    u16* __restrict__ Vp)
{
  __shared__ __align__(16) short smem[15360];  // 30,720 B
  short* Ah = smem;            // [128][40]
  short* Al = smem + 5120;     // [128][40]
  short* Bh = smem + 10240;    // [64][40]
  short* Bl = smem + 12800;    // [64][40]

  const int t = threadIdx.x;
  const int m0 = blockIdx.x * 128;
  const int n0g = blockIdx.y * 64;           // global col in [0, 3072)
  const int proj = n0g >> 10;
  const int nloc = n0g & (E_ - 1);
  const float* A = (proj == 0) ? q : (proj == 1) ? k : v;
  const bool split = (proj < 2);

  const int w = t >> 6, lane = t & 63;
  const int g = lane >> 4, lc = lane & 15;
  const int wm = w & 1, wn = w >> 1;
  const int sra = t >> 1, sca = (t & 1) * 16; // A staging: 2 thr/row, 16 f32
  const int srb = t >> 2, scb = (t & 3) * 8;  // B staging: 4 thr/row, 8 u16

  const float* Abp = A + (size_t)(m0 + sra) * E_ + sca;
  const u16* Bhb = WHi + (size_t)(n0g + srb) * E_ + scb;
  const u16* Blb = WLo + (size_t)(n0g + srb) * E_ + scb;

  f32x4 acc[4][2];
#pragma unroll
  for (int i = 0; i < 4; ++i)
#pragma unroll
    for (int j = 0; j < 2; ++j) acc[i][j] = (f32x4){0.f, 0.f, 0.f, 0.f};

  // prefetch registers
  float4 ar[4]; short8 br, cr;
#pragma unroll
  for (int i = 0; i < 4; ++i) ar[i] = *(const float4*)(Abp + 4 * i);
  br = *(const short8*)(Bhb);
  if (split) cr = *(const short8*)(Blb);

  for (int k0 = 0; k0 < E_; k0 += 32) {
    __syncthreads();                 // previous iteration's frag reads done
    // store staged regs -> LDS (A converted hi/lo by truncation split)
#pragma unroll
    for (int i = 0; i < 4; ++i) {
      ushort4 h, l;
      tsplit(ar[i].x, h.x, l.x); tsplit(ar[i].y, h.y, l.y);
      tsplit(ar[i].z, h.z, l.z); tsplit(ar[i].w, h.w, l.w);
      *(ushort4*)&Ah[sra * 40 + sca + 4 * i] = h;
      if (split) *(ushort4*)&Al[sra * 40 + sca + 4 * i] = l;
    }
    *(short8*)&Bh[srb * 40 + scb] = br;
    if (split) *(short8*)&Bl[srb * 40 + scb] = cr;
    __syncthreads();
    // prefetch next K-step (latency hidden behind frag reads + MFMA)
    if (k0 + 32 < E_) {
#pragma unroll
      for (int i = 0; i < 4; ++i) ar[i] = *(const float4*)(Abp + k0 + 32 + 4 * i);
      br = *(const short8*)(Bhb + k0 + 32);
      if (split) cr = *(const short8*)(Blb + k0 + 32);
    }

    short8 ah[4], al[4], bh[2], bl[2];
#pragma unroll
    for (int mt = 0; mt < 4; ++mt) {
      const int ro = (wm * 64 + mt * 16 + lc) * 40 + g * 8;
      ah[mt] = *(const short8*)&Ah[ro];
      if (split) al[mt] = *(const short8*)&Al[ro];
    }
#pragma unroll
    for (int nt = 0; nt < 2; ++nt) {
      const int ro = (wn * 32 + nt * 16 + lc) * 40 + g * 8;
      bh[nt] = *(const short8*)&Bh[ro];
      if (split) bl[nt] = *(const short8*)&Bl[ro];
    }
#pragma unroll
    for (int mt = 0; mt < 4; ++mt)
#pragma unroll
      for (int nt = 0; nt < 2; ++nt) {
        f32x4 a = acc[mt][nt];
        a = __builtin_amdgcn_mfma_f32_16x16x32_bf16(ah[mt], bh[nt], a, 0, 0, 0);
        if (split) {
          a = __builtin_amdgcn_mfma_f32_16x16x32_bf16(ah[mt], bl[nt], a, 0, 0, 0);
          a = __builtin_amdgcn_mfma_f32_16x16x32_bf16(al[mt], bh[nt], a, 0, 0, 0);
        }
        acc[mt][nt] = a;
      }
  }

  // epilogue
  float bs[2];
#pragma unroll
  for (int nt = 0; nt < 2; ++nt) bs[nt] = bias[n0g + wn * 32 + nt * 16 + lc];

  if (proj < 2) {
    // block's 64 n-cols = exactly one head; wave covers d-range wn*32..+31
    u16* Hi = (proj == 0) ? QpHi : KpHi;
    u16* Lo = (proj == 0) ? QpLo : KpLo;
    const int head = nloc >> 6;
    short* T = smem + w * 2560;               // per-wave [64][40] u16
    const int mrow = m0 + wm * 64 + lane;
    const int bb = mrow >> 11, s = mrow & (S_ - 1);
    bool ok = true;
    int srow_out = s;
    if (proj == 1) {                          // K: compact rows
      ok = (Msk[bb * S_ + s] != 0);
      srow_out = Cpos[bb * S_ + s];
    }
    const size_t rowb = (((size_t)(bb * H_ + head)) * S_ + srow_out) * D_ + wn * 32;
#pragma unroll
    for (int pass = 0; pass < 2; ++pass) {
      __syncthreads();                        // LDS free / prev pass reads done
#pragma unroll
      for (int nt = 0; nt < 2; ++nt)
#pragma unroll
        for (int mt = 0; mt < 4; ++mt)
#pragma unroll
          for (int r = 0; r < 4; ++r) {
            const float val = acc[mt][nt][r] + bs[nt];
            const uint32_t u = __float_as_uint(val);
            u16 x;
            if (pass == 0) x = (u16)(u >> 16);
            else {
              const float hif = __uint_as_float(u & 0xFFFF0000u);
              x = (u16)(__float_as_uint(val - hif) >> 16);
            }
            T[(mt * 16 + g * 4 + r) * 40 + nt * 16 + lc] = (short)x;
          }
      __syncthreads();
      u16* dst = (pass == 0) ? Hi : Lo;
      if (ok) {
#pragma unroll
        for (int j = 0; j < 4; ++j)
          *(short8*)&dst[rowb + 8 * j] = *(const short8*)&T[lane * 40 + 8 * j];
      }
    }
  } else {
    // V: [B,H,D,S] layout with key columns compacted (predicated scalar stores)
#pragma unroll
    for (int mt = 0; mt < 4; ++mt) {
      const int mrow = m0 + wm * 64 + mt * 16 + g * 4;
      const int bb = mrow >> 11, sbase = mrow & (S_ - 1);
      const int4 mk = *(const int4*)&Msk[bb * S_ + sbase];
      const int4 cp = *(const int4*)&Cpos[bb * S_ + sbase];
      const int mkA[4] = {mk.x, mk.y, mk.z, mk.w};
      const int cpA[4] = {cp.x, cp.y, cp.z, cp.w};
#pragma unroll
      for (int nt = 0; nt < 2; ++nt) {
        const int nE = nloc + wn * 32 + nt * 16 + lc;
        const int h = nE >> 6, d = nE & 63;
        const size_t rb = (((size_t)(bb * H_ + h)) * D_ + d) * S_;
#pragma unroll
        for (int r = 0; r < 4; ++r) {
          if (mkA[r]) Vp[rb + cpA[r]] = f2bf(acc[mt][nt][r] + bs[nt]);
        }
      }
    }
  }
}

// ---------------------------------------------------------------------------
// Kernel 2: MFMA flash attention v5 (unchanged from round 1).
// ---------------------------------------------------------------------------
__global__ __launch_bounds__(256, 4) void attn_mfma_kernel(
    const u16* __restrict__ QpHi, const u16* __restrict__ QpLo,
    const u16* __restrict__ KpHi, const u16* __restrict__ KpLo,
    const u16* __restrict__ Vp,
    const int* __restrict__ nkArr,
    u16* __restrict__ AOHi)
{
  __shared__ __align__(16) short sm[18432];  // 36,864 B
  short* Khi = sm;                           // [64][72]
  short* Klo = sm + 4608;                    // [64][72]
  short* Vt  = sm + 9216;                    // [64][72] (d-major)
  short* Pb  = sm + 13824;                   // 4 waves x [16][72]

  const int t = threadIdx.x;
  const int w = t >> 6, lane = t & 63;
  const int g = lane >> 4, lc = lane & 15;
  const int bh = blockIdx.y;
  const int b = bh >> 4, hh = bh & 15;
  const int q0 = blockIdx.x * 64;
  const size_t hb = (size_t)bh * S_ * D_;
  const u16* QgH = QpHi + hb;
  const u16* QgL = QpLo + hb;
  const u16* KgH = KpHi + hb;
  const u16* KgL = KpLo + hb;
  const u16* Vg  = Vp + hb;
  short* Pw = Pb + w * 1152;

  const int nk = nkArr[b];
  const int kend = ((nk + 63) >> 6) << 6;    // tiles of 64 compacted keys

  // ---- Q A-frags direct from global (lane lc = q-row, k = 8g..8g+7) ----
  short8 qh[2], ql[2];
  {
    const size_t base = (size_t)(q0 + 16 * w + lc) * D_ + 8 * g;
    qh[0] = *(const short8*)&QgH[base];
    qh[1] = *(const short8*)&QgH[base + 32];
    ql[0] = *(const short8*)&QgL[base];
    ql[1] = *(const short8*)&QgL[base + 32];
  }

  // ones column in B (n=0): lanes with lc==0 hold bf16(1.0) for all k
  short8 ones8 = {0, 0, 0, 0, 0, 0, 0, 0};
  if (lc == 0) {
    const short o = (short)0x3F80;
    ones8 = (short8){o, o, o, o, o, o, o, o};
  }

  f32x4 O[4];
  f32x4 Ol = (f32x4){0.f, 0.f, 0.f, 0.f};
#pragma unroll
  for (int dt = 0; dt < 4; ++dt) O[dt] = (f32x4){0.f, 0.f, 0.f, 0.f};
  float mst[4] = {-INFINITY, -INFINITY, -INFINITY, -INFINITY};

  const int srow = t >> 2, sc16 = (t & 3) * 16;   // staging: 4 threads/row

  // staging prefetch registers (K hi/lo, V)
  short8 kr[2], lr[2], vr[2];
  kr[0] = *(const short8*)&KgH[srow * D_ + sc16];
  kr[1] = *(const short8*)&KgH[srow * D_ + sc16 + 8];
  lr[0] = *(const short8*)&KgL[srow * D_ + sc16];
  lr[1] = *(const short8*)&KgL[srow * D_ + sc16 + 8];
  vr[0] = *(const short8*)&Vg[srow * S_ + sc16];
  vr[1] = *(const short8*)&Vg[srow * S_ + sc16 + 8];

  for (int kt = 0; kt < kend; kt += 64) {
    __syncthreads();                         // previous tile fully consumed
    *(short8*)&Khi[srow * 72 + sc16]     = kr[0];
    *(short8*)&Khi[srow * 72 + sc16 + 8] = kr[1];
    *(short8*)&Klo[srow * 72 + sc16]     = lr[0];
    *(short8*)&Klo[srow * 72 + sc16 + 8] = lr[1];
    *(short8*)&Vt[srow * 72 + sc16]      = vr[0];
    *(short8*)&Vt[srow * 72 + sc16 + 8]  = vr[1];
    __syncthreads();
    if (kt + 64 < kend) {                    // prefetch next tile
      const int kn = kt + 64;
      kr[0] = *(const short8*)&KgH[(kn + srow) * D_ + sc16];
      kr[1] = *(const short8*)&KgH[(kn + srow) * D_ + sc16 + 8];
      lr[0] = *(const short8*)&KgL[(kn + srow) * D_ + sc16];
      lr[1] = *(const short8*)&KgL[(kn + srow) * D_ + sc16 + 8];
      vr[0] = *(const short8*)&Vg[srow * S_ + kn + sc16];
      vr[1] = *(const short8*)&Vg[srow * S_ + kn + sc16 + 8];
    }

    // ---- scores: S[16q x 64k] ----
    f32x4 sc[4];
#pragma unroll
    for (int kt16 = 0; kt16 < 4; ++kt16) {
      const int ko = (16 * kt16 + lc) * 72 + 8 * g;
      const short8 kh0 = *(const short8*)&Khi[ko];
      const short8 kh1 = *(const short8*)&Khi[ko + 32];
      const short8 kl0 = *(const short8*)&Klo[ko];
      const short8 kl1 = *(const short8*)&Klo[ko + 32];
      f32x4 a = {0.f, 0.f, 0.f, 0.f};
      a = __builtin_amdgcn_mfma_f32_16x16x32_bf16(qh[0], kh0, a, 0, 0, 0);
      a = __builtin_amdgcn_mfma_f32_16x16x32_bf16(qh[1], kh1, a, 0, 0, 0);
      a = __builtin_amdgcn_mfma_f32_16x16x32_bf16(qh[0], kl0, a, 0, 0, 0);
      a = __builtin_amdgcn_mfma_f32_16x16x32_bf16(qh[1], kl1, a, 0, 0, 0);
      a = __builtin_amdgcn_mfma_f32_16x16x32_bf16(ql[0], kh0, a, 0, 0, 0);
      a = __builtin_amdgcn_mfma_f32_16x16x32_bf16(ql[1], kh1, a, 0, 0, 0);
      sc[kt16] = a;
    }

    // ---- tail masking: compacted cols >= nk are padding (garbage K) ----
    if (kt + 64 > nk) {
#pragma unroll
      for (int kt16 = 0; kt16 < 4; ++kt16) {
        if (kt + 16 * kt16 + lc >= nk) {
          sc[kt16][0] = -1e20f; sc[kt16][1] = -1e20f;
          sc[kt16][2] = -1e20f; sc[kt16][3] = -1e20f;
        }
      }
    }

    // ---- online max + exp (max butterfly only; sum comes from MFMA) ----
    float al[4];
#pragma unroll
    for (int r = 0; r < 4; ++r) {
      float vv = fmaxf(fmaxf(sc[0][r], sc[1][r]), fmaxf(sc[2][r], sc[3][r]));
      vv = fmaxf(vv, __shfl_xor(vv, 1));
      vv = fmaxf(vv, __shfl_xor(vv, 2));
      vv = fmaxf(vv, __shfl_xor(vv, 4));
      vv = fmaxf(vv, __shfl_xor(vv, 8));
      const float mn = fmaxf(mst[r], vv);
      al[r] = __expf(mst[r] - mn);           // first tile: exp(-inf)=0
      mst[r] = mn;
    }
#pragma unroll
    for (int kt16 = 0; kt16 < 4; ++kt16) {
#pragma unroll
      for (int r = 0; r < 4; ++r)
        sc[kt16][r] = __expf(sc[kt16][r] - mst[r]);
    }
    const f32x4 alv = {al[0], al[1], al[2], al[3]};
    O[0] *= alv; O[1] *= alv; O[2] *= alv; O[3] *= alv;
    Ol *= alv;
    // P: C-layout regs -> bf16 LDS (A-layout source for PV)
#pragma unroll
    for (int kt16 = 0; kt16 < 4; ++kt16) {
#pragma unroll
      for (int r = 0; r < 4; ++r)
        Pw[(4 * g + r) * 72 + 16 * kt16 + lc] = (short)f2bf(sc[kt16][r]);
    }

    // ---- PV + denominator via ones ----
    short8 pa[2];
    pa[0] = *(const short8*)&Pw[lc * 72 + 8 * g];
    pa[1] = *(const short8*)&Pw[lc * 72 + 32 + 8 * g];
    Ol = __builtin_amdgcn_mfma_f32_16x16x32_bf16(pa[0], ones8, Ol, 0, 0, 0);
    Ol = __builtin_amdgcn_mfma_f32_16x16x32_bf16(pa[1], ones8, Ol, 0, 0, 0);
#pragma unroll
    for (int dt = 0; dt < 4; ++dt) {
      const int vo = (16 * dt + lc) * 72 + 8 * g;
      const short8 vb0 = *(const short8*)&Vt[vo];
      const short8 vb1 = *(const short8*)&Vt[vo + 32];
      O[dt] = __builtin_amdgcn_mfma_f32_16x16x32_bf16(pa[0], vb0, O[dt], 0, 0, 0);
      O[dt] = __builtin_amdgcn_mfma_f32_16x16x32_bf16(pa[1], vb1, O[dt], 0, 0, 0);
    }
  }

  // ---- epilogue: broadcast denominator (col 0 on lanes lc==0), normalize ----
#pragma unroll
  for (int r = 0; r < 4; ++r) {
    const float lv = __shfl(Ol[r], lane & 48);
    const float lir = 1.0f / lv;
    const int qrow = q0 + 16 * w + 4 * g + r;
    const size_t rowb = (size_t)(b * S_ + qrow) * E_ + hh * 64;
#pragma unroll
    for (int dt = 0; dt < 4; ++dt)
      AOHi[rowb + dt * 16 + lc] = f2bf(O[dt][r] * lir);
  }
}

// ---------------------------------------------------------------------------
// Kernel 3: output projection, single-bf16 MFMA, register prefetch.
// ---------------------------------------------------------------------------
__global__ __launch_bounds__(256) void gemm_out_kernel(
    const u16* __restrict__ AHi,
    const u16* __restrict__ WHi,
    const float* __restrict__ bias, float* __restrict__ out)
{
  __shared__ __align__(16) short Ah[128 * 40];
  __shared__ __align__(16) short Bh[128 * 40];

  const int t = threadIdx.x;
  const int m0 = blockIdx.x * 128;
  const int n0 = blockIdx.y * 128;
  const int w = t >> 6, lane = t & 63;
  const int g = lane >> 4, lc = lane & 15;
  const int wm = w & 1, wn = w >> 1;
  const int srow = t >> 1, sh = (t & 1) * 16;

  const u16* Ahb = AHi + (size_t)(m0 + srow) * E_ + sh;
  const u16* Bhb = WHi + (size_t)(n0 + srow) * E_ + sh;

  f32x4 acc[4][4];
#pragma unroll
  for (int i = 0; i < 4; ++i)
#pragma unroll
    for (int j = 0; j < 4; ++j) acc[i][j] = (f32x4){0.f, 0.f, 0.f, 0.f};

  short8 arr[2], brr[2];
  arr[0] = *(const short8*)(Ahb); arr[1] = *(const short8*)(Ahb + 8);
  brr[0] = *(const short8*)(Bhb); brr[1] = *(const short8*)(Bhb + 8);

  for (int k0 = 0; k0 < E_; k0 += 32) {
    __syncthreads();
    *(short8*)&Ah[srow * 40 + sh]     = arr[0];
    *(short8*)&Ah[srow * 40 + sh + 8] = arr[1];
    *(short8*)&Bh[srow * 40 + sh]     = brr[0];
    *(short8*)&Bh[srow * 40 + sh + 8] = brr[1];
    __syncthreads();
    if (k0 + 32 < E_) {
      arr[0] = *(const short8*)(Ahb + k0 + 32); arr[1] = *(const short8*)(Ahb + k0 + 40);
      brr[0] = *(const short8*)(Bhb + k0 + 32); brr[1] = *(const short8*)(Bhb + k0 + 40);
    }

    short8 ah[4], bh[4];
#pragma unroll
    for (int mt = 0; mt < 4; ++mt)
      ah[mt] = *(const short8*)&Ah[(wm * 64 + mt * 16 + lc) * 40 + g * 8];
#pragma unroll
    for (int nt = 0; nt < 4; ++nt)
      bh[nt] = *(const short8*)&Bh[(wn * 64 + nt * 16 + lc) * 40 + g * 8];
#pragma unroll
    for (int mt = 0; mt < 4; ++mt)
#pragma unroll
      for (int nt = 0; nt < 4; ++nt)
        acc[mt][nt] = __builtin_amdgcn_mfma_f32_16x16x32_bf16(ah[mt], bh[nt], acc[mt][nt], 0, 0, 0);
  }

  float bs[4];
#pragma unroll
  for (int nt = 0; nt < 4; ++nt) bs[nt] = bias[n0 + wn * 64 + nt * 16 + lc];
#pragma unroll
  for (int nt = 0; nt < 4; ++nt) {
    const int nc = n0 + wn * 64 + nt * 16 + lc;
#pragma unroll
    for (int mt = 0; mt < 4; ++mt) {
#pragma unroll
      for (int r = 0; r < 4; ++r) {
        const int mrow = m0 + wm * 64 + mt * 16 + g * 4 + r;
        out[(size_t)mrow * E_ + nc] = acc[mt][nt][r] + bs[nt];
      }
    }
  }
}

// ---------------------------------------------------------------------------
extern "C" void kernel_launch(void* const* d_in, const int* in_sizes, int n_in,
                              void* d_out, int out_size, void* d_ws, size_t ws_size,
                              hipStream_t stream) {
  const float* q    = (const float*)d_in[0];
  const float* k    = (const float*)d_in[1];
  const float* v    = (const float*)d_in[2];
  const int*   mask = (const int*)d_in[3];
  const float* Wqkv = (const float*)d_in[4];
  const float* bqkv = (const float*)d_in[5];
  const float* Wout = (const float*)d_in[6];
  const float* bout = (const float*)d_in[7];
  float* out = (float*)d_out;

  // Workspace layout (64 MB).
  char* wsb = (char*)d_ws;
  u16* WqkvHi = (u16*)(wsb + 0);          //  6 MB
  u16* WqkvLo = (u16*)(wsb + 6291456);    //  6 MB
  u16* WoutHi = (u16*)(wsb + 12582912);   //  2 MB
  // WoutLo region (2 MB at 14680064) is scratch: split writes it, then the
  // scan kernel reuses the space for cpos/nk (stream-ordered, safe).
  int* Cpos   = (int*)(wsb + 14680064);   // 16 KB (B*S ints)
  int* Nk     = (int*)(wsb + 14680064 + 16384);  // 8 B
  u16* WoutLo = (u16*)(wsb + 14680064);   // (written then overwritten, unused)
  u16* QpHi   = (u16*)(wsb + 16777216);   //  8 MB
  u16* QpLo   = (u16*)(wsb + 25165824);   //  8 MB
  u16* KpHi   = (u16*)(wsb + 33554432);   //  8 MB
  u16* KpLo   = (u16*)(wsb + 41943040);   //  8 MB
  u16* Vp     = (u16*)(wsb + 50331648);   //  8 MB
  u16* AOHi   = (u16*)(wsb + 58720256);   //  8 MB

  hipLaunchKernelGGL(split_f32_kernel, dim3(3072), dim3(256), 0, stream,
                     Wqkv, WqkvHi, WqkvLo, 786432);
  hipLaunchKernelGGL(split_f32_kernel, dim3(1024), dim3(256), 0, stream,
                     Wout, WoutHi, WoutLo, 262144);
  hipLaunchKernelGGL(mask_scan_kernel, dim3(B_), dim3(256), 0, stream,
                     mask, Cpos, Nk);
  // zero V so padded tail columns (>= nk) contribute exact 0 in PV
  hipMemsetAsync(Vp, 0, 8388608, stream);
  hipLaunchKernelGGL(gemm_qkv_kernel, dim3(M_ / 128, 48), dim3(256), 0, stream,
                     q, k, v, WqkvHi, WqkvLo, bqkv, mask, Cpos,
                     QpHi, QpLo, KpHi, KpLo, Vp);
  hipLaunchKernelGGL(attn_mfma_kernel, dim3(S_ / 64, B_ * H_), dim3(256), 0, stream,
                     QpHi, QpLo, KpHi, KpLo, Vp, Nk, AOHi);
  hipLaunchKernelGGL(gemm_out_kernel, dim3(M_ / 128, E_ / 128), dim3(256), 0, stream,
                     AOHi, WoutHi, bout, out);
}